// Round 6
// baseline (7894.244 us; speedup 1.0000x reference)
//
#include <hip/hip_runtime.h>
#include <cstdint>
#include <cmath>

typedef unsigned short u16;
typedef unsigned long long u64;
typedef __attribute__((ext_vector_type(8))) short short8;
typedef __attribute__((ext_vector_type(4))) float f32x4;

#define SEQ 1024
#define HD 1024
#define GD 4096
#define NB 8
#define MROWS 8192   // NB*SEQ

__device__ __forceinline__ u16 f2bf(float f) {
  union { float f; uint32_t u; } c; c.f = f;
  uint32_t u = c.u;
  uint32_t r = (u + 0x7fffu + ((u >> 16) & 1u)) >> 16;
  return (u16)r;
}
__device__ __forceinline__ float bf2f(u16 h) {
  union { uint32_t u; float f; } c; c.u = ((uint32_t)h) << 16;
  return c.f;
}

// ---------------- fp32 -> bf16 convert ----------------
__global__ void k_tobf16(const float* __restrict__ in, u16* __restrict__ out, long n) {
  long i = ((long)blockIdx.x * 256L + threadIdx.x) * 4;
  long st = (long)gridDim.x * 1024L;
  for (; i < n; i += st) {
    float4 v = *(const float4*)(in + i);
    ushort4 o;
    o.x = f2bf(v.x); o.y = f2bf(v.y); o.z = f2bf(v.z); o.w = f2bf(v.w);
    *(ushort4*)(out + i) = o;
  }
}

// ---------------- bf16 MFMA GEMM: C[m][n] = sum_k A[m][k]*Bw[n][k] (+epilogue) ----
// MODE 0: outb[(t*8+b)*4096 + col] = bf16(acc + bias[n])   (t-major relayout for scan)
// MODE 1: outf = gelu(acc + bias[n]) + res[m][n]           (exact gelu)
template<int MODE>
__global__ __launch_bounds__(256, 1) void k_gemm(
    const u16* __restrict__ A, const u16* __restrict__ Bw,
    const float* __restrict__ bias, const float* __restrict__ res,
    u16* __restrict__ outb, float* __restrict__ outf, int N, int K)
{
  __shared__ u16 As[128][40];
  __shared__ u16 Bs[128][40];
  const int tid = threadIdx.x;
  const int wid = tid >> 6, lane = tid & 63;
  const int wm = wid >> 1, wn = wid & 1;
  const int r = lane & 15, q = lane >> 4;
  const long m0 = (long)blockIdx.y * 128, n0 = (long)blockIdx.x * 128;
  const int srow = tid >> 1, sseg = (tid & 1) * 16;

  f32x4 acc[4][4];
#pragma unroll
  for (int i = 0; i < 4; ++i)
#pragma unroll
    for (int j = 0; j < 4; ++j) acc[i][j] = (f32x4){0.f, 0.f, 0.f, 0.f};

  const u16* ag = A + (m0 + srow) * (long)K + sseg;
  const u16* bg = Bw + (n0 + srow) * (long)K + sseg;

  for (int k0 = 0; k0 < K; k0 += 32) {
    short8 av0 = *(const short8*)(ag + k0);
    short8 av1 = *(const short8*)(ag + k0 + 8);
    short8 bv0 = *(const short8*)(bg + k0);
    short8 bv1 = *(const short8*)(bg + k0 + 8);
    __syncthreads();
    *(short8*)&As[srow][sseg]     = av0;
    *(short8*)&As[srow][sseg + 8] = av1;
    *(short8*)&Bs[srow][sseg]     = bv0;
    *(short8*)&Bs[srow][sseg + 8] = bv1;
    __syncthreads();
    short8 bfr[4];
#pragma unroll
    for (int ni = 0; ni < 4; ++ni)
      bfr[ni] = *(const short8*)&Bs[wn * 64 + ni * 16 + r][q * 8];
#pragma unroll
    for (int mi = 0; mi < 4; ++mi) {
      short8 afr = *(const short8*)&As[wm * 64 + mi * 16 + r][q * 8];
#pragma unroll
      for (int ni = 0; ni < 4; ++ni)
        acc[mi][ni] = __builtin_amdgcn_mfma_f32_16x16x32_bf16(afr, bfr[ni], acc[mi][ni], 0, 0, 0);
    }
  }

#pragma unroll
  for (int mi = 0; mi < 4; ++mi)
#pragma unroll
    for (int ni = 0; ni < 4; ++ni) {
      long col = n0 + wn * 64 + ni * 16 + r;
      float bc = bias[col];
#pragma unroll
      for (int rr = 0; rr < 4; ++rr) {
        long row = m0 + wm * 64 + mi * 16 + q * 4 + rr;
        float v = acc[mi][ni][rr] + bc;
        if (MODE == 0) {
          long b = row >> 10, t = row & 1023;
          outb[((t * 8 + b) << 12) + col] = f2bf(v);
        } else {
          float ge = 0.5f * v * (1.0f + erff(v * 0.70710678118654752f));
          outf[row * N + col] = ge + res[row * N + col];
        }
      }
    }
}

// ---------------- persistent sLSTM scan, batch-partitioned ----------------
// 256 WGs x 576 threads (9 waves). WG wgid: b = wgid&7 (batch -> likely XCD b),
// c = wgid>>3 (unit chunk). 8 independent groups of 32 WGs.
// h exchange: tagged u64 published to BOTH an XCD-local L2 mirror (plain sc0
// store, read with sc0 loads - fast iff writer/reader share the XCD L2) AND an
// agent-scope buffer (always-correct fallback). Readers try the mirror 6x,
// then fall back. Wrong placement costs a bounded few hundred cycles per step;
// right placement turns the detect leg into an L2 round trip.
__global__ __launch_bounds__(576, 1) void k_scan(
    const u16* __restrict__ xp, const u16* __restrict__ Rb,
    u16* __restrict__ hseq, uint32_t* __restrict__ hx, uint32_t* __restrict__ hxm,
    int tagbase)
{
  __shared__ float Dred[2][8][128];   // [par][wave][g*32+u]
  __shared__ u16 xpf[4][4][32];       // [t&3][g][u]
  __shared__ u16 hhist[32][32];       // [t&31][u]

  const int tid = threadIdx.x;
  const int wgid = blockIdx.x;
  const int b = wgid & 7, c = wgid >> 3;
  const int wid = tid >> 6, lane = tid & 63;
  const int r = lane & 15, q = lane >> 4;

  // ---- weights G2R: wave w holds k in [w*128,(w+1)*128) for 128 local rows.
  short8 wt[8][4];
  if (wid < 8) {
#pragma unroll
    for (int j = 0; j < 8; ++j) {
      const int coll = j * 16 + r;
      const int g = coll >> 5, u = coll & 31;
      const u16* src = Rb + ((long)(g * HD + c * 32 + u)) * HD + wid * 128 + q * 8;
#pragma unroll
      for (int s = 0; s < 4; ++s)
        wt[j][s] = *(const short8*)(src + s * 32);
    }
  }
  // prologue: xpf[0],xpf[1]
  if (wid == 8 && lane < 32) {
    const int g = lane >> 3, o4 = (lane & 7) * 4;
#pragma unroll
    for (int t = 0; t < 2; ++t) {
      u64 v = *(const u64*)(xp + ((long)(t * 8 + b) << 12) + g * 1024 + c * 32 + o4);
      *(u64*)&xpf[t][g][o4] = v;
    }
  }
  __syncthreads();

  float c_s = 0.f, n_s = 0.f, m_s = 0.f;
  u64* hxq  = (u64*)hx;
  u64* hxqm = (u64*)hxm;

  for (int i = 0; i < SEQ; ++i) {
    if (wid < 8) {
      if (i + 1 < SEQ) {
        // issue xp[i+2] prefetch first (wave 0)
        u64 xv = 0;
        const int g0 = lane >> 3, o4 = (lane & 7) * 4;
        if (wid == 0 && lane < 32 && i + 2 < SEQ)
          xv = *(const u64*)(xp + ((long)((i + 2) * 8 + b) << 12) + g0 * 1024 + c * 32 + o4);

        // poll own u64 of h_i: mirror fast lane (sc0/L2), then agent fallback
        const unsigned tg = (unsigned)(tagbase + i) & 0xffffu;
        const long ofs = (long)(b * 2 + (i & 1)) * 512 + wid * 64 + lane;
        const u64 am = (u64)(uintptr_t)(hxqm + ofs);
        u64 hv = 0;
        bool need = true;
#pragma unroll 1
        for (int p2 = 0; p2 < 6 && __any(need); ++p2) {
          u64 t2;
          asm volatile("global_load_dwordx2 %0, %1, off sc0\n\ts_waitcnt vmcnt(0)"
                       : "=v"(t2) : "v"(am) : "memory");
          if (need && ((((unsigned)(t2 >> 16)) & 0xffffu) == tg) &&
              (((unsigned)(t2 >> 48)) == tg)) { hv = t2; need = false; }
        }
#pragma unroll 1
        while (__any(need)) {
          u64 t2 = __hip_atomic_load(hxq + ofs, __ATOMIC_RELAXED, __HIP_MEMORY_SCOPE_AGENT);
          if (need && ((((unsigned)(t2 >> 16)) & 0xffffu) == tg) &&
              (((unsigned)(t2 >> 48)) == tg)) { hv = t2; need = false; }
        }
        unsigned pk = ((unsigned)hv & 0xffffu) | (((unsigned)(hv >> 32) & 0xffffu) << 16);

        // MFMA: A row 0 = h k-slice; B = wt
        f32x4 acc[8];
#pragma unroll
        for (int j = 0; j < 8; ++j) acc[j] = (f32x4){0.f, 0.f, 0.f, 0.f};
#pragma unroll
        for (int s = 0; s < 4; ++s) {
          union { unsigned x[4]; short8 v; } af;
#pragma unroll
          for (int m2 = 0; m2 < 4; ++m2)
            af.x[m2] = __shfl(pk, s * 16 + q * 4 + m2, 64);
#pragma unroll
          for (int j = 0; j < 8; ++j)
            acc[j] = __builtin_amdgcn_mfma_f32_16x16x32_bf16(af.v, wt[j][s], acc[j], 0, 0, 0);
        }
        const int par = (i + 1) & 1;
        if (q == 0) {
#pragma unroll
          for (int j = 0; j < 8; ++j)
            Dred[par][wid][j * 16 + r] = acc[j][0];
        }
        if (wid == 0 && lane < 32 && i + 2 < SEQ)
          *(u64*)&xpf[(i + 2) & 3][g0][o4] = xv;
      }
    } else {
      // ---- gate wave: lanes 0-31 = units
      unsigned word = 0;
      if (lane < 32) {
        const int u = lane;
        float pre[4];
#pragma unroll
        for (int g = 0; g < 4; ++g) {
          float s2 = bf2f(xpf[i & 3][g][u]);
          if (i > 0) {
#pragma unroll
            for (int w = 0; w < 8; ++w) s2 += Dred[i & 1][w][g * 32 + u];
          }
          pre[g] = s2;
        }
        float mn = fmaxf(pre[1] + m_s, pre[0]);
        float ig = __expf(pre[0] - mn);
        float fg = __expf(pre[1] + m_s - mn);
        float e2 = __expf(2.f * pre[2]);
        float th = 1.f - 2.f / (e2 + 1.f);
        c_s = fg * c_s + ig * th;
        n_s = fg * n_s + ig;
        m_s = mn;
        float og = 1.f / (1.f + __expf(-pre[3]));
        float h = og * (c_s / n_s);
        word = ((unsigned)((tagbase + i) & 0xffff) << 16) | (unsigned)f2bf(h);
      }
      // publish: mirror (sc0, XCD-local L2) first, then agent copy
      unsigned wa = __shfl(word, (lane * 2) & 63, 64);
      unsigned wb = __shfl(word, (lane * 2 + 1) & 63, 64);
      if (lane < 16 && i < SEQ - 1) {
        u64 v64 = (u64)wa | ((u64)wb << 32);
        const long ofs = (long)(b * 2 + (i & 1)) * 512 + c * 16 + lane;
        const u64 am = (u64)(uintptr_t)(hxqm + ofs);
        asm volatile("global_store_dwordx2 %0, %1, off sc0"
                     :: "v"(am), "v"(v64) : "memory");
        __hip_atomic_store(hxq + ofs, v64, __ATOMIC_RELAXED, __HIP_MEMORY_SCOPE_AGENT);
      }
      // history + amortized hseq dump (off critical path)
      if (lane < 32) hhist[i & 31][lane] = (u16)(word & 0xffffu);
      if ((i & 31) == 31 && lane < 32) {
#pragma unroll
        for (int j = 0; j < 4; ++j) {
          short8 v = *(const short8*)&hhist[lane][j * 8];
          *(short8*)(hseq + ((long)(b * SEQ + (i - 31 + lane))) * HD + c * 32 + j * 8) = v;
        }
      }
    }
    __syncthreads();
  }
}

// ---------------- row LayerNorm (D=1024), fp32 out + bf16 copy ----------------
__global__ __launch_bounds__(256, 1) void k_ln(
    const float* __restrict__ z, const float* __restrict__ gamma, const float* __restrict__ beta,
    float* __restrict__ xout, u16* __restrict__ xb)
{
  const int row = blockIdx.x, tid = threadIdx.x;
  const float4 v = *(const float4*)(z + (long)row * HD + tid * 4);
  float s = v.x + v.y + v.z + v.w;
  float s2 = v.x * v.x + v.y * v.y + v.z * v.z + v.w * v.w;
#pragma unroll
  for (int off = 32; off > 0; off >>= 1) {
    s += __shfl_down(s, off, 64);
    s2 += __shfl_down(s2, off, 64);
  }
  __shared__ float red[8];
  const int wid = tid >> 6, lane = tid & 63;
  if (lane == 0) { red[wid] = s; red[4 + wid] = s2; }
  __syncthreads();
  float su = red[0] + red[1] + red[2] + red[3];
  float sq = red[4] + red[5] + red[6] + red[7];
  float mu = su * (1.f / 1024.f);
  float var = sq * (1.f / 1024.f) - mu * mu;
  float rs = rsqrtf(var + 1e-5f);
  const float4 g  = *(const float4*)(gamma + tid * 4);
  const float4 bt = *(const float4*)(beta + tid * 4);
  float4 o;
  o.x = (v.x - mu) * rs * g.x + bt.x;
  o.y = (v.y - mu) * rs * g.y + bt.y;
  o.z = (v.z - mu) * rs * g.z + bt.z;
  o.w = (v.w - mu) * rs * g.w + bt.w;
  *(float4*)(xout + (long)row * HD + tid * 4) = o;
  ushort4 ob;
  ob.x = f2bf(o.x); ob.y = f2bf(o.y); ob.z = f2bf(o.z); ob.w = f2bf(o.w);
  *(ushort4*)(xb + (long)row * HD + tid * 4) = ob;
}

// ---------------- launch ----------------
extern "C" void kernel_launch(void* const* d_in, const int* in_sizes, int n_in,
                              void* d_out, int out_size, void* d_ws, size_t ws_size,
                              hipStream_t stream)
{
  const float* input = (const float*)d_in[0];
  const float* W[2]  = { (const float*)d_in[1], (const float*)d_in[8] };
  const float* R[2]  = { (const float*)d_in[2], (const float*)d_in[9] };
  const float* bb[2] = { (const float*)d_in[3], (const float*)d_in[10] };
  const float* pW[2] = { (const float*)d_in[4], (const float*)d_in[11] };
  const float* pb[2] = { (const float*)d_in[5], (const float*)d_in[12] };
  const float* gm[2] = { (const float*)d_in[6], (const float*)d_in[13] };
  const float* bt[2] = { (const float*)d_in[7], (const float*)d_in[14] };
  float* out = (float*)d_out;

  char* p = (char*)d_ws;
  size_t off = 0;
  auto alloc = [&](size_t bytes) { char* q = p + off; off += (bytes + 255) & ~(size_t)255; return (void*)q; };
  uint32_t* hx  = (uint32_t*)alloc(NB * 2 * HD * 4);   // tagged h words (agent)
  uint32_t* hxm = (uint32_t*)alloc(NB * 2 * HD * 4);   // tagged h words (L2 mirror)
  u16* xb     = (u16*)alloc((size_t)MROWS * HD * 2);
  u16* Wb[2]  = { (u16*)alloc((size_t)GD * HD * 2), (u16*)alloc((size_t)GD * HD * 2) };
  u16* Rbv[2] = { (u16*)alloc((size_t)GD * HD * 2), (u16*)alloc((size_t)GD * HD * 2) };
  u16* pWb[2] = { (u16*)alloc((size_t)HD * HD * 2), (u16*)alloc((size_t)HD * HD * 2) };
  u16* xpb    = (u16*)alloc((size_t)MROWS * GD * 2);
  u16* hs     = (u16*)alloc((size_t)MROWS * HD * 2);
  float* zb   = (float*)alloc((size_t)MROWS * HD * 4);
  float* x1   = (float*)alloc((size_t)MROWS * HD * 4);

  auto conv = [&](const float* src, u16* dst, long n) {
    int blocks = (int)((n / 4 + 255) / 256); if (blocks > 2048) blocks = 2048;
    k_tobf16<<<dim3(blocks), dim3(256), 0, stream>>>(src, dst, n);
  };
  conv(input, xb, (long)MROWS * HD);
  conv(W[0], Wb[0], (long)GD * HD);  conv(W[1], Wb[1], (long)GD * HD);
  conv(R[0], Rbv[0], (long)GD * HD); conv(R[1], Rbv[1], (long)GD * HD);
  conv(pW[0], pWb[0], (long)HD * HD); conv(pW[1], pWb[1], (long)HD * HD);

  // poison both exchange buffers (0xAAAA tag never targeted)
  hipMemsetAsync(hx,  0xAA, NB * 2 * HD * 4, stream);
  hipMemsetAsync(hxm, 0xAA, NB * 2 * HD * 4, stream);

  for (int l = 0; l < 2; ++l) {
    // xp = x @ W.T + b  -> bf16, t-major layout
    k_gemm<0><<<dim3(GD / 128, MROWS / 128), 256, 0, stream>>>(
        xb, Wb[l], bb[l], nullptr, xpb, nullptr, GD, HD);
    // sLSTM scan: 256 WGs, 8 independent batch groups of 32
    k_scan<<<dim3(256), dim3(576), 0, stream>>>(xpb, Rbv[l], hs, hx, hxm, l * 1024);
    // z = gelu(hseq @ pW.T + pb) + x_res
    const float* resp = (l == 0) ? input : x1;
    k_gemm<1><<<dim3(HD / 128, MROWS / 128), 256, 0, stream>>>(
        hs, pWb[l], pb[l], resp, nullptr, zb, HD, HD);
    // layernorm -> fp32 x_next (+ bf16 copy for next layer's GEMM1)
    float* xo = (l == 0) ? x1 : out;
    k_ln<<<dim3(MROWS), dim3(256), 0, stream>>>(zb, gm[l], bt[l], xo, xb);
  }
}

// Round 7
// 5269.205 us; speedup vs baseline: 1.4982x; 1.4982x over previous
//
#include <hip/hip_runtime.h>
#include <cstdint>
#include <cmath>

typedef unsigned short u16;
typedef unsigned long long u64;
typedef __attribute__((ext_vector_type(8))) short short8;
typedef __attribute__((ext_vector_type(4))) float f32x4;

#define SEQ 1024
#define HD 1024
#define GD 4096
#define NB 8
#define MROWS 8192   // NB*SEQ

__device__ __forceinline__ u16 f2bf(float f) {
  union { float f; uint32_t u; } c; c.f = f;
  uint32_t u = c.u;
  uint32_t r = (u + 0x7fffu + ((u >> 16) & 1u)) >> 16;
  return (u16)r;
}
__device__ __forceinline__ float bf2f(u16 h) {
  union { uint32_t u; float f; } c; c.u = ((uint32_t)h) << 16;
  return c.f;
}

// ---------------- fp32 -> bf16 convert ----------------
__global__ void k_tobf16(const float* __restrict__ in, u16* __restrict__ out, long n) {
  long i = ((long)blockIdx.x * 256L + threadIdx.x) * 4;
  long st = (long)gridDim.x * 1024L;
  for (; i < n; i += st) {
    float4 v = *(const float4*)(in + i);
    ushort4 o;
    o.x = f2bf(v.x); o.y = f2bf(v.y); o.z = f2bf(v.z); o.w = f2bf(v.w);
    *(ushort4*)(out + i) = o;
  }
}

// ---------------- bf16 MFMA GEMM: C[m][n] = sum_k A[m][k]*Bw[n][k] (+epilogue) ----
// MODE 0: outb[(t*8+b)*4096 + col] = bf16(acc + bias[n])   (t-major relayout for scan)
// MODE 1: outf = gelu(acc + bias[n]) + res[m][n]           (exact gelu)
template<int MODE>
__global__ __launch_bounds__(256, 1) void k_gemm(
    const u16* __restrict__ A, const u16* __restrict__ Bw,
    const float* __restrict__ bias, const float* __restrict__ res,
    u16* __restrict__ outb, float* __restrict__ outf, int N, int K)
{
  __shared__ u16 As[128][40];
  __shared__ u16 Bs[128][40];
  const int tid = threadIdx.x;
  const int wid = tid >> 6, lane = tid & 63;
  const int wm = wid >> 1, wn = wid & 1;
  const int r = lane & 15, q = lane >> 4;
  const long m0 = (long)blockIdx.y * 128, n0 = (long)blockIdx.x * 128;
  const int srow = tid >> 1, sseg = (tid & 1) * 16;

  f32x4 acc[4][4];
#pragma unroll
  for (int i = 0; i < 4; ++i)
#pragma unroll
    for (int j = 0; j < 4; ++j) acc[i][j] = (f32x4){0.f, 0.f, 0.f, 0.f};

  const u16* ag = A + (m0 + srow) * (long)K + sseg;
  const u16* bg = Bw + (n0 + srow) * (long)K + sseg;

  for (int k0 = 0; k0 < K; k0 += 32) {
    short8 av0 = *(const short8*)(ag + k0);
    short8 av1 = *(const short8*)(ag + k0 + 8);
    short8 bv0 = *(const short8*)(bg + k0);
    short8 bv1 = *(const short8*)(bg + k0 + 8);
    __syncthreads();
    *(short8*)&As[srow][sseg]     = av0;
    *(short8*)&As[srow][sseg + 8] = av1;
    *(short8*)&Bs[srow][sseg]     = bv0;
    *(short8*)&Bs[srow][sseg + 8] = bv1;
    __syncthreads();
    short8 bfr[4];
#pragma unroll
    for (int ni = 0; ni < 4; ++ni)
      bfr[ni] = *(const short8*)&Bs[wn * 64 + ni * 16 + r][q * 8];
#pragma unroll
    for (int mi = 0; mi < 4; ++mi) {
      short8 afr = *(const short8*)&As[wm * 64 + mi * 16 + r][q * 8];
#pragma unroll
      for (int ni = 0; ni < 4; ++ni)
        acc[mi][ni] = __builtin_amdgcn_mfma_f32_16x16x32_bf16(afr, bfr[ni], acc[mi][ni], 0, 0, 0);
    }
  }

#pragma unroll
  for (int mi = 0; mi < 4; ++mi)
#pragma unroll
    for (int ni = 0; ni < 4; ++ni) {
      long col = n0 + wn * 64 + ni * 16 + r;
      float bc = bias[col];
#pragma unroll
      for (int rr = 0; rr < 4; ++rr) {
        long row = m0 + wm * 64 + mi * 16 + q * 4 + rr;
        float v = acc[mi][ni][rr] + bc;
        if (MODE == 0) {
          long b = row >> 10, t = row & 1023;
          outb[((t * 8 + b) << 12) + col] = f2bf(v);
        } else {
          float ge = 0.5f * v * (1.0f + erff(v * 0.70710678118654752f));
          outf[row * N + col] = ge + res[row * N + col];
        }
      }
    }
}

// ---------------- persistent sLSTM scan, batch-partitioned, 8 waves ----------
// 256 WGs x 512 threads (8 waves -> 2 waves/SIMD -> 256-VGPR cap so the
// 128-VGPR weight block stays REGISTER-RESIDENT, no scratch spill).
// b = wgid&7, c = wgid>>3 (owns units [c*32,(c+1)*32) of batch b).
// Waves 0-7: k-slice w*128; per step poll 1 flag per 8-lane group, one agent
//   u64 load of h, shfl-built A-frag, 32 MFMAs, Dred partials (parity ring).
// Wave 7 additionally: after the single barrier, gates + state + publish h
//   directly into hseq (acked agent stores + per-WG flag).
// Wave 0 additionally: xp prefetch ring (depth 4).
__global__ __launch_bounds__(512, 1) void k_scan(
    const u16* __restrict__ xp, const u16* __restrict__ Rb,
    u16* __restrict__ hseq, unsigned* __restrict__ flags, int tagbase)
{
  __shared__ float Dred[2][8][128];   // [par][wave][g*32+u]
  __shared__ u16 xpf[4][4][32];       // [t&3][g][u]

  const int tid = threadIdx.x;
  const int wgid = blockIdx.x;
  const int b = wgid & 7, c = wgid >> 3;
  const int w = tid >> 6, lane = tid & 63;
  const int r = lane & 15, q = lane >> 4;

  // ---- weights G2R: wave w holds k in [w*128,(w+1)*128) for 128 local rows.
  // local row j*16+r -> gate g = (j*16+r)>>5, unit u = (j*16+r)&31.
  short8 wt[8][4];
#pragma unroll
  for (int j = 0; j < 8; ++j) {
    const int coll = j * 16 + r;
    const int g = coll >> 5, u = coll & 31;
    const u16* src = Rb + ((long)(g * HD + c * 32 + u)) * HD + w * 128 + q * 8;
#pragma unroll
    for (int s = 0; s < 4; ++s)
      wt[j][s] = *(const short8*)(src + s * 32);
  }

  // zero Dred (gates_0 path safety)
  {
    float* dz = &Dred[0][0][0];
    for (int k2 = tid; k2 < 2 * 8 * 128; k2 += 512) dz[k2] = 0.f;
  }
  // prologue: xpf[0],xpf[1]  (xp t-major: ((t*8+b)<<12) + g*1024 + c*32 + u)
  if (w == 0 && lane < 32) {
    const int g = lane >> 3, o4 = (lane & 7) * 4;
#pragma unroll
    for (int t = 0; t < 2; ++t) {
      u64 v = *(const u64*)(xp + ((long)(t * 8 + b) << 12) + g * 1024 + c * 32 + o4);
      *(u64*)&xpf[t][g][o4] = v;
    }
  }
  __syncthreads();

  float c_s = 0.f, n_s = 0.f, m_s = 0.f;

  for (int i = 0; i < SEQ; ++i) {
    // ---- phase A (all 8 waves): Dred[i&1] = h_{i-1} @ R^T partials (i>=1)
    if (i > 0) {
      u64 hv = 0;
      if (lane < 32) {
        const int writer = w * 4 + (lane >> 3);      // 8 u64 per writer WG
        const unsigned tgt = (unsigned)(tagbase + i);
        while (__hip_atomic_load(&flags[(b * 32 + writer) << 4],
                                 __ATOMIC_RELAXED, __HIP_MEMORY_SCOPE_AGENT) < tgt) {}
        asm volatile("" ::: "memory");
        const u64* hrow = (const u64*)(hseq + ((long)(b * SEQ + (i - 1))) * HD);
        hv = __hip_atomic_load(hrow + w * 32 + lane,
                               __ATOMIC_RELAXED, __HIP_MEMORY_SCOPE_AGENT);
      }
      f32x4 acc[8];
#pragma unroll
      for (int j = 0; j < 8; ++j) acc[j] = (f32x4){0.f, 0.f, 0.f, 0.f};
#pragma unroll
      for (int s = 0; s < 4; ++s) {
        union { u64 q2[2]; short8 v; } af;
        af.q2[0] = __shfl(hv, s * 8 + q * 2, 64);
        af.q2[1] = __shfl(hv, s * 8 + q * 2 + 1, 64);
#pragma unroll
        for (int j = 0; j < 8; ++j)
          acc[j] = __builtin_amdgcn_mfma_f32_16x16x32_bf16(af.v, wt[j][s], acc[j], 0, 0, 0);
      }
      if (q == 0) {
#pragma unroll
        for (int j = 0; j < 8; ++j)
          Dred[i & 1][w][j * 16 + r] = acc[j][0];    // D row 0
      }
    }
    __syncthreads();

    // ---- phase C: wave 7 = gates + publish; wave 0 = xp prefetch
    if (w == 7) {
      const int u = lane & 31;
      float pre[4];
#pragma unroll
      for (int g = 0; g < 4; ++g) {
        float s2 = bf2f(xpf[i & 3][g][u]);
        if (i > 0) {
#pragma unroll
          for (int w2 = 0; w2 < 8; ++w2) s2 += Dred[i & 1][w2][g * 32 + u];
        }
        pre[g] = s2;
      }
      float mn = fmaxf(pre[1] + m_s, pre[0]);
      float ig = __expf(pre[0] - mn);
      float fg = __expf(pre[1] + m_s - mn);
      float e2 = __expf(2.f * pre[2]);
      float th = 1.f - 2.f / (e2 + 1.f);             // tanh(pre[2])
      c_s = fg * c_s + ig * th;
      n_s = fg * n_s + ig;
      m_s = mn;
      float og = 1.f / (1.f + __expf(-pre[3]));
      float h = og * (c_s / n_s);

      unsigned hu = (unsigned)f2bf(h);
      // pack 4 units/u64, publish into hseq (exchange + GEMM2 input in one)
      unsigned lo2 = hu | (__shfl_down(hu, 1) << 16);
      u64 v64 = (u64)lo2 | ((u64)__shfl_down(lo2, 2) << 32);
      if (lane < 32 && (lane & 3) == 0) {
        u64* dst = (u64*)(hseq + ((long)(b * SEQ + i)) * HD) + c * 8 + (lane >> 2);
        __hip_atomic_store(dst, v64, __ATOMIC_RELAXED, __HIP_MEMORY_SCOPE_AGENT);
      }
      asm volatile("s_waitcnt vmcnt(0)" ::: "memory");   // data at coherence point
      if (lane == 0)
        __hip_atomic_store(&flags[(b * 32 + c) << 4], (unsigned)(tagbase + i + 1),
                           __ATOMIC_RELAXED, __HIP_MEMORY_SCOPE_AGENT);
    } else if (w == 0 && lane < 32 && i + 2 < SEQ) {
      const int g = lane >> 3, o4 = (lane & 7) * 4;
      u64 v = *(const u64*)(xp + ((long)((i + 2) * 8 + b) << 12) + g * 1024 + c * 32 + o4);
      *(u64*)&xpf[(i + 2) & 3][g][o4] = v;
    }
    // no trailing barrier: Dred parity + xpf depth-4 ring + flag protocol
    // make next iteration's phase A race-free; waves 0-6 poll while wave 7
    // gates/publishes (intra-WG skew <= 1 step, bounded by phase-A barrier).
  }
}

// ---------------- row LayerNorm (D=1024), fp32 out + bf16 copy ----------------
__global__ __launch_bounds__(256, 1) void k_ln(
    const float* __restrict__ z, const float* __restrict__ gamma, const float* __restrict__ beta,
    float* __restrict__ xout, u16* __restrict__ xb)
{
  const int row = blockIdx.x, tid = threadIdx.x;
  const float4 v = *(const float4*)(z + (long)row * HD + tid * 4);
  float s = v.x + v.y + v.z + v.w;
  float s2 = v.x * v.x + v.y * v.y + v.z * v.z + v.w * v.w;
#pragma unroll
  for (int off = 32; off > 0; off >>= 1) {
    s += __shfl_down(s, off, 64);
    s2 += __shfl_down(s2, off, 64);
  }
  __shared__ float red[8];
  const int wid = tid >> 6, lane = tid & 63;
  if (lane == 0) { red[wid] = s; red[4 + wid] = s2; }
  __syncthreads();
  float su = red[0] + red[1] + red[2] + red[3];
  float sq = red[4] + red[5] + red[6] + red[7];
  float mu = su * (1.f / 1024.f);
  float var = sq * (1.f / 1024.f) - mu * mu;
  float rs = rsqrtf(var + 1e-5f);
  const float4 g  = *(const float4*)(gamma + tid * 4);
  const float4 bt = *(const float4*)(beta + tid * 4);
  float4 o;
  o.x = (v.x - mu) * rs * g.x + bt.x;
  o.y = (v.y - mu) * rs * g.y + bt.y;
  o.z = (v.z - mu) * rs * g.z + bt.z;
  o.w = (v.w - mu) * rs * g.w + bt.w;
  *(float4*)(xout + (long)row * HD + tid * 4) = o;
  ushort4 ob;
  ob.x = f2bf(o.x); ob.y = f2bf(o.y); ob.z = f2bf(o.z); ob.w = f2bf(o.w);
  *(ushort4*)(xb + (long)row * HD + tid * 4) = ob;
}

// ---------------- launch ----------------
extern "C" void kernel_launch(void* const* d_in, const int* in_sizes, int n_in,
                              void* d_out, int out_size, void* d_ws, size_t ws_size,
                              hipStream_t stream)
{
  const float* input = (const float*)d_in[0];
  const float* W[2]  = { (const float*)d_in[1], (const float*)d_in[8] };
  const float* R[2]  = { (const float*)d_in[2], (const float*)d_in[9] };
  const float* bb[2] = { (const float*)d_in[3], (const float*)d_in[10] };
  const float* pW[2] = { (const float*)d_in[4], (const float*)d_in[11] };
  const float* pb[2] = { (const float*)d_in[5], (const float*)d_in[12] };
  const float* gm[2] = { (const float*)d_in[6], (const float*)d_in[13] };
  const float* bt[2] = { (const float*)d_in[7], (const float*)d_in[14] };
  float* out = (float*)d_out;

  char* p = (char*)d_ws;
  size_t off = 0;
  auto alloc = [&](size_t bytes) { char* q = p + off; off += (bytes + 255) & ~(size_t)255; return (void*)q; };
  unsigned* flags = (unsigned*)alloc(256 * 64);        // 256 writer WGs x 64B pad
  u16* xb     = (u16*)alloc((size_t)MROWS * HD * 2);
  u16* Wb[2]  = { (u16*)alloc((size_t)GD * HD * 2), (u16*)alloc((size_t)GD * HD * 2) };
  u16* Rbv[2] = { (u16*)alloc((size_t)GD * HD * 2), (u16*)alloc((size_t)GD * HD * 2) };
  u16* pWb[2] = { (u16*)alloc((size_t)HD * HD * 2), (u16*)alloc((size_t)HD * HD * 2) };
  u16* xpb    = (u16*)alloc((size_t)MROWS * GD * 2);
  u16* hs     = (u16*)alloc((size_t)MROWS * HD * 2);
  float* zb   = (float*)alloc((size_t)MROWS * HD * 4);
  float* x1   = (float*)alloc((size_t)MROWS * HD * 4);

  auto conv = [&](const float* src, u16* dst, long n) {
    int blocks = (int)((n / 4 + 255) / 256); if (blocks > 2048) blocks = 2048;
    k_tobf16<<<dim3(blocks), dim3(256), 0, stream>>>(src, dst, n);
  };
  conv(input, xb, (long)MROWS * HD);
  conv(W[0], Wb[0], (long)GD * HD);  conv(W[1], Wb[1], (long)GD * HD);
  conv(R[0], Rbv[0], (long)GD * HD); conv(R[1], Rbv[1], (long)GD * HD);
  conv(pW[0], pWb[0], (long)HD * HD); conv(pW[1], pWb[1], (long)HD * HD);

  // reset flags once per launch; tagbase keeps layers disjoint within a launch
  hipMemsetAsync(flags, 0, 256 * 64, stream);

  for (int l = 0; l < 2; ++l) {
    // xp = x @ W.T + b  -> bf16, t-major layout
    k_gemm<0><<<dim3(GD / 128, MROWS / 128), 256, 0, stream>>>(
        xb, Wb[l], bb[l], nullptr, xpb, nullptr, GD, HD);
    // sLSTM scan: 256 WGs x 512 threads, 8 batch groups of 32
    k_scan<<<dim3(256), dim3(512), 0, stream>>>(xpb, Rbv[l], hs, flags, l * 1024);
    // z = gelu(hseq @ pW.T + pb) + x_res
    const float* resp = (l == 0) ? input : x1;
    k_gemm<1><<<dim3(HD / 128, MROWS / 128), 256, 0, stream>>>(
        hs, pWb[l], pb[l], resp, nullptr, zb, HD, HD);
    // layernorm -> fp32 x_next (+ bf16 copy for next layer's GEMM1)
    float* xo = (l == 0) ? x1 : out;
    k_ln<<<dim3(MROWS), dim3(256), 0, stream>>>(zb, gm[l], bt[l], xo, xb);
  }
}